// Round 4
// baseline (152.801 us; speedup 1.0000x reference)
//
#include <hip/hip_runtime.h>
#include <math.h>

// Problem constants (match reference)
#define N_NODES 50000
#define N_EDGES 800000
#define DFEAT   128
#define MAXNORM (1.0f - 4e-3f)   // (1 - BALL_EPS)/sqrt(c), c=1
#define CAP     32               // padded adjacency slots per row (deg ~ Poisson(16); P(deg>32)~1e-4 -> ovf)
#define OVF_CAP 8192
#define NPART   8                // row partitions (~XCDs)
#define PSIZE   (N_NODES / NPART) // 6250 rows per partition
#define SENT    N_NODES          // sentinel node id (xb row is zeros)

// clang-native vector type: __builtin_nontemporal_* accepts these (HIP_vector_type float4 is rejected)
typedef float vfloat4 __attribute__((ext_vector_type(4)));

// ==================== tier 1: partitioned build + pre-scaled bf16 gather ====================

__device__ __forceinline__ void build_edge(int r, int c, int lo, int hi,
                                           int* __restrict__ deg,
                                           unsigned short* __restrict__ adj16,
                                           int* __restrict__ ovf, int* __restrict__ ovf_cnt) {
    if (r < lo || r >= hi || r == c) return;
    int pos = atomicAdd(&deg[r], 1);
    if (pos < CAP) adj16[r * CAP + pos] = (unsigned short)c;
    else {
        int o = atomicAdd(ovf_cnt, 1);
        if (o < OVF_CAP) { ovf[2 * o] = r; ovf[2 * o + 1] = c; }
    }
}

// Row-partitioned build (r11-proven): blocks with (blockIdx&7)==p handle only
// rows in partition p; with the blockIdx%8->XCD round-robin heuristic each
// partition's deg atomics + adj stores stay in ONE XCD's L2 (no cross-XCD
// line bouncing). All partitions scan all edges via int4 loads (4 edges per
// thread-iteration -> 4x fewer load instructions in the 8x redundant scan).
__global__ void k_build(const int* __restrict__ row, const int* __restrict__ col,
                        int* __restrict__ deg, unsigned short* __restrict__ adj16,
                        int* __restrict__ ovf, int* __restrict__ ovf_cnt, int e) {
    int p      = blockIdx.x & (NPART - 1);
    int vblock = blockIdx.x >> 3;
    int tpp    = (gridDim.x >> 3) * blockDim.x;       // threads per partition
    int tid    = vblock * blockDim.x + threadIdx.x;   // 0..tpp-1 within partition
    int lo = p * PSIZE, hi = lo + PSIZE;

    int e4 = e >> 2;
    const int4* __restrict__ row4 = (const int4*)row;
    const int4* __restrict__ col4 = (const int4*)col;
    for (int i = tid; i < e4; i += tpp) {
        int4 r4 = row4[i];
        int4 c4 = col4[i];
        build_edge(r4.x, c4.x, lo, hi, deg, adj16, ovf, ovf_cnt);
        build_edge(r4.y, c4.y, lo, hi, deg, adj16, ovf, ovf_cnt);
        build_edge(r4.z, c4.z, lo, hi, deg, adj16, ovf, ovf_cnt);
        build_edge(r4.w, c4.w, lo, hi, deg, adj16, ovf, ovf_cnt);
    }
    // scalar tail (empty when e % 4 == 0)
    for (int i = (e4 << 2) + tid; i < e; i += tpp)
        build_edge(row[i], col[i], lo, hi, deg, adj16, ovf, ovf_cnt);
}

// After build: xb[node] = bf16(x[node] * rsqrt(deg[node]+1)); row N_NODES = zeros.
// 16 threads per row (8 floats each).
__global__ __launch_bounds__(256) void k_prep(const float* __restrict__ x,
                                              const int* __restrict__ deg,
                                              unsigned int* __restrict__ xb,   // packed 2x bf16 per word
                                              int nthreads) {
    int t = blockIdx.x * blockDim.x + threadIdx.x;
    if (t >= nthreads) return;

    int node = t >> 4;            // 16 threads per row
    int part = t & 15;            // which 8-float chunk
    unsigned int w[4];
    if (node < N_NODES) {
        float dis = rsqrtf((float)(deg[node] + 1));
        const vfloat4* x4 = (const vfloat4*)(x + (size_t)node * DFEAT + part * 8);
        vfloat4 a = __builtin_nontemporal_load(x4);      // x is read once; don't pollute L2
        vfloat4 b = __builtin_nontemporal_load(x4 + 1);
        float fs[8] = {a.x, a.y, a.z, a.w, b.x, b.y, b.z, b.w};
        #pragma unroll
        for (int k = 0; k < 4; ++k) {
            unsigned int lo = __float_as_uint(fs[2 * k] * dis);
            unsigned int hi = __float_as_uint(fs[2 * k + 1] * dis);
            lo = (lo + 0x7FFFu + ((lo >> 16) & 1u)) >> 16;          // RNE to bf16
            hi = (hi + 0x7FFFu + ((hi >> 16) & 1u)) >> 16;
            w[k] = lo | (hi << 16);
        }
    } else {
        w[0] = w[1] = w[2] = w[3] = 0u;   // sentinel row: zeros
    }
    ((uint4*)xb)[t] = make_uint4(w[0], w[1], w[2], w[3]);
}

__device__ __forceinline__ float bf_lo(unsigned int w) { return __uint_as_float(w << 16); }
__device__ __forceinline__ float bf_hi(unsigned int w) { return __uint_as_float(w & 0xFFFF0000u); }

// One wave per destination row. Neighbors processed in chunks of 16 (8
// independent uint2 loads per half-wave, batch-issued -> ONE latency wait per
// chunk). Chunk 2 is gated on the wave-uniform capcnt>16 (P~0.43 for
// Poisson(16)) -> expected 1.43 chunks/row. deg>32 rows (~1e-4) go through
// the overflow list, scanned ONLY by those rows (cnt>CAP gate).
__global__ __launch_bounds__(256) void k_gather_bf(const unsigned int* __restrict__ xb,
                                                   const unsigned short* __restrict__ adj16,
                                                   const int* __restrict__ deg,
                                                   const int* __restrict__ ovf,
                                                   const int* __restrict__ ovf_cnt,
                                                   float* __restrict__ out, int n) {
    int lane = threadIdx.x & 63;
    int half = lane >> 5;
    int fl   = lane & 31;
    int rowi = blockIdx.x * 4 + (threadIdx.x >> 6);
    if (rowi >= n) return;

    int cnt    = deg[rowi];
    int capcnt = cnt < CAP ? cnt : CAP;

    int a = SENT;
    if (lane < capcnt) a = (int)adj16[rowi * CAP + lane];  // coalesced 64B per row

    const unsigned int* __restrict__ xw = xb + 2 * fl;     // lane's word pair base

    // issue the self-row load early; it completes under the neighbor batches
    uint2 sv = *(const uint2*)(xw + rowi * (DFEAT / 2));

    float acc0 = 0.f, acc1 = 0.f, acc2 = 0.f, acc3 = 0.f;

    // chunk 1: neighbors 0..15 (8 independent loads per lane, one batch)
    {
        int c[8];
        #pragma unroll
        for (int j = 0; j < 8; ++j) c[j] = __shfl(a, 2 * j + half);
        uint2 v[8];
        #pragma unroll
        for (int j = 0; j < 8; ++j) v[j] = *(const uint2*)(xw + c[j] * (DFEAT / 2));
        #pragma unroll
        for (int j = 0; j < 8; ++j) {
            acc0 += bf_lo(v[j].x); acc1 += bf_hi(v[j].x);
            acc2 += bf_lo(v[j].y); acc3 += bf_hi(v[j].y);
        }
    }
    // chunk 2: neighbors 16..31 (wave-uniform branch, P ~ 0.43)
    if (capcnt > 16) {
        int c[8];
        #pragma unroll
        for (int j = 0; j < 8; ++j) c[j] = __shfl(a, 16 + 2 * j + half);
        uint2 v[8];
        #pragma unroll
        for (int j = 0; j < 8; ++j) v[j] = *(const uint2*)(xw + c[j] * (DFEAT / 2));
        #pragma unroll
        for (int j = 0; j < 8; ++j) {
            acc0 += bf_lo(v[j].x); acc1 += bf_hi(v[j].x);
            acc2 += bf_lo(v[j].y); acc3 += bf_hi(v[j].y);
        }
    }

    // overflow edges: only rows that actually overflowed scan the list
    if (cnt > CAP && half == 0) {
        int novf = *ovf_cnt;
        for (int k = 0; k < novf; ++k) {
            if (ovf[2 * k] == rowi) {
                uint2 v = *(const uint2*)(xw + ovf[2 * k + 1] * (DFEAT / 2));
                acc0 += bf_lo(v.x); acc1 += bf_hi(v.x);
                acc2 += bf_lo(v.y); acc3 += bf_hi(v.y);
            }
        }
    }

    // combine halves (afterwards both halves hold identical full sums)
    acc0 += __shfl_xor(acc0, 32);
    acc1 += __shfl_xor(acc1, 32);
    acc2 += __shfl_xor(acc2, 32);
    acc3 += __shfl_xor(acc3, 32);

    // self term: xb[rowi] pre-scaled by dis[rowi]
    acc0 += bf_lo(sv.x); acc1 += bf_hi(sv.x);
    acc2 += bf_lo(sv.y); acc3 += bf_hi(sv.y);

    float di = rsqrtf((float)(cnt + 1));             // dis[row]
    acc0 *= di; acc1 *= di; acc2 *= di; acc3 *= di;

    // norm^2: reduce within each 32-half (halves identical)
    float nsq = acc0 * acc0 + acc1 * acc1 + acc2 * acc2 + acc3 * acc3;
    #pragma unroll
    for (int off = 16; off > 0; off >>= 1) nsq += __shfl_xor(nsq, off);

    float un = fmaxf(sqrtf(nsq), 1e-15f);
    float th = tanhf(un);
    float scale = th / un;                           // expmap0
    if (th > MAXNORM) scale *= MAXNORM / th;         // proj clamp (||p|| == tanh(un))

    if (half == 0) {
        vfloat4 o = { acc0 * scale, acc1 * scale, acc2 * scale, acc3 * scale };
        // written once, never re-read: non-temporal keeps xb resident in L2
        __builtin_nontemporal_store(o, (vfloat4*)(out + (size_t)rowi * DFEAT + 4 * fl));
    }
}

// ==================== fallback: CSR path (proven round-2) ====================

#define SCAN_BLK 256
#define NUM_SCAN_BLOCKS ((N_NODES + SCAN_BLK - 1) / SCAN_BLK)

__global__ void k_init_deg(int* __restrict__ deg, int n) {
    int i = blockIdx.x * blockDim.x + threadIdx.x;
    if (i < n) deg[i] = 1;
}

__global__ void k_hist(const int* __restrict__ row, const int* __restrict__ col,
                       int* __restrict__ deg, int e) {
    int i = blockIdx.x * blockDim.x + threadIdx.x;
    if (i < e) {
        int r = row[i], c = col[i];
        if (r != c) atomicAdd(&deg[r], 1);
    }
}

__global__ __launch_bounds__(SCAN_BLK) void k_block_sums(const int* __restrict__ deg,
                                                         int* __restrict__ blockSums, int n) {
    __shared__ int s[SCAN_BLK];
    int t = threadIdx.x;
    int i = blockIdx.x * SCAN_BLK + t;
    s[t] = (i < n) ? (deg[i] - 1) : 0;
    __syncthreads();
    for (int off = SCAN_BLK / 2; off > 0; off >>= 1) {
        if (t < off) s[t] += s[t + off];
        __syncthreads();
    }
    if (t == 0) blockSums[blockIdx.x] = s[0];
}

__global__ __launch_bounds__(SCAN_BLK) void k_scan_blocks(const int* __restrict__ blockSums,
                                                          int* __restrict__ blockBase) {
    __shared__ int s[SCAN_BLK];
    int t = threadIdx.x;
    s[t] = (t < NUM_SCAN_BLOCKS) ? blockSums[t] : 0;
    __syncthreads();
    for (int off = 1; off < SCAN_BLK; off <<= 1) {
        int v = (t >= off) ? s[t - off] : 0;
        __syncthreads();
        s[t] += v;
        __syncthreads();
    }
    if (t < NUM_SCAN_BLOCKS) blockBase[t] = (t == 0) ? 0 : s[t - 1];
}

__global__ __launch_bounds__(SCAN_BLK) void k_block_scan(const int* __restrict__ deg,
                                                         const int* __restrict__ blockBase,
                                                         int* __restrict__ offs,
                                                         int* __restrict__ cursor, int n) {
    __shared__ int s[SCAN_BLK];
    int t = threadIdx.x;
    int i = blockIdx.x * SCAN_BLK + t;
    int cnt = (i < n) ? (deg[i] - 1) : 0;
    s[t] = cnt;
    __syncthreads();
    for (int off = 1; off < SCAN_BLK; off <<= 1) {
        int v = (t >= off) ? s[t - off] : 0;
        __syncthreads();
        s[t] += v;
        __syncthreads();
    }
    if (i < n) {
        int excl = s[t] - cnt + blockBase[blockIdx.x];
        offs[i]   = excl;
        cursor[i] = excl;
    }
}

__global__ void k_scatter(const int* __restrict__ row, const int* __restrict__ col,
                          int* __restrict__ cursor, int* __restrict__ adj, int e) {
    int i = blockIdx.x * blockDim.x + threadIdx.x;
    if (i < e) {
        int r = row[i], c = col[i];
        if (r != c) {
            int pos = atomicAdd(&cursor[r], 1);
            adj[pos] = c;
        }
    }
}

__global__ __launch_bounds__(256) void k_gather_csr(const float* __restrict__ x,
                                                    const int* __restrict__ adj,
                                                    const int* __restrict__ offs,
                                                    const int* __restrict__ deg,
                                                    float* __restrict__ out, int n) {
    int lane = threadIdx.x & 63;
    int rowi = blockIdx.x * 4 + (threadIdx.x >> 6);
    if (rowi >= n) return;

    const float2* __restrict__ x2 = (const float2*)x;
    int beg = offs[rowi];
    int cnt = deg[rowi] - 1;

    float2 acc = make_float2(0.0f, 0.0f);
    for (int base = 0; base < cnt; base += 64) {
        int m = cnt - base; if (m > 64) m = 64;
        int a = 0;
        if (lane < m) a = adj[beg + base + lane];
        for (int nb = 0; nb < m; ++nb) {
            int c = __shfl(a, nb);
            float w = rsqrtf((float)deg[c]);
            float2 v = x2[c * (DFEAT / 2) + lane];
            acc.x += w * v.x;
            acc.y += w * v.y;
        }
    }
    float di = rsqrtf((float)deg[rowi]);
    float2 self = x2[rowi * (DFEAT / 2) + lane];
    acc.x = di * (acc.x + di * self.x);
    acc.y = di * (acc.y + di * self.y);

    float nsq = acc.x * acc.x + acc.y * acc.y;
    #pragma unroll
    for (int off = 32; off > 0; off >>= 1) nsq += __shfl_xor(nsq, off);

    float un = fmaxf(sqrtf(nsq), 1e-15f);
    float th = tanhf(un);
    float scale = th / un;
    if (th > MAXNORM) scale *= MAXNORM / th;

    float2 o = make_float2(acc.x * scale, acc.y * scale);
    ((float2*)out)[rowi * (DFEAT / 2) + lane] = o;
}

// ==================== launcher ====================

extern "C" void kernel_launch(void* const* d_in, const int* in_sizes, int n_in,
                              void* d_out, int out_size, void* d_ws, size_t ws_size,
                              hipStream_t stream) {
    const float* x          = (const float*)d_in[0];
    const int*   edge_index = (const int*)d_in[1];
    const int*   row = edge_index;            // [E]
    const int*   col = edge_index + N_EDGES;  // [E]
    float* out = (float*)d_out;
    char*  ws  = (char*)d_ws;

    size_t sz_xb    = sizeof(unsigned short) * (size_t)(N_NODES + 1) * DFEAT;  // 12.80 MB
    size_t sz_adj16 = sizeof(unsigned short) * (size_t)N_NODES * CAP;          //  3.20 MB
    size_t sz_deg   = sizeof(int) * (size_t)N_NODES;
    size_t need = sz_xb + sz_adj16 + sz_deg + sizeof(int) * (1 + 2 * (size_t)OVF_CAP);

    dim3 blk(256);
    if (ws_size >= need) {
        size_t off = 0;
        unsigned int*   xb      = (unsigned int*)(ws + off);   off += sz_xb;
        unsigned short* adj16   = (unsigned short*)(ws + off); off += sz_adj16;
        int*            deg     = (int*)(ws + off);            off += sz_deg;
        int*            ovf_cnt = (int*)(ws + off);            off += sizeof(int);
        int*            ovf     = (int*)(ws + off);

        int nprep = (N_NODES + 1) * (DFEAT / 8);   // 16 threads per row incl. sentinel
        // deg and ovf_cnt are contiguous: one stream-ordered memset (graph-capturable)
        // replaces the k_zero launch.
        hipMemsetAsync(deg, 0, sz_deg + sizeof(int), stream);
        k_build<<<dim3(8192), blk, 0, stream>>>(row, col, deg, adj16, ovf, ovf_cnt, N_EDGES);
        k_prep<<<dim3((nprep + 255) / 256), blk, 0, stream>>>(x, deg, xb, nprep);
        k_gather_bf<<<dim3((N_NODES + 3) / 4), blk, 0, stream>>>(xb, adj16, deg, ovf, ovf_cnt, out, N_NODES);
    } else {
        size_t off = 0;
        int* deg       = (int*)(ws + off); off += sizeof(int) * (size_t)N_NODES;
        int* offs      = (int*)(ws + off); off += sizeof(int) * (size_t)N_NODES;
        int* cursor    = (int*)(ws + off); off += sizeof(int) * (size_t)N_NODES;
        int* blockSums = (int*)(ws + off); off += sizeof(int) * (size_t)NUM_SCAN_BLOCKS;
        int* blockBase = (int*)(ws + off); off += sizeof(int) * (size_t)NUM_SCAN_BLOCKS;
        int* adj       = (int*)(ws + off);

        k_init_deg<<<dim3((N_NODES + 255) / 256), blk, 0, stream>>>(deg, N_NODES);
        k_hist<<<dim3((N_EDGES + 255) / 256), blk, 0, stream>>>(row, col, deg, N_EDGES);
        k_block_sums<<<dim3(NUM_SCAN_BLOCKS), dim3(SCAN_BLK), 0, stream>>>(deg, blockSums, N_NODES);
        k_scan_blocks<<<dim3(1), dim3(SCAN_BLK), 0, stream>>>(blockSums, blockBase);
        k_block_scan<<<dim3(NUM_SCAN_BLOCKS), dim3(SCAN_BLK), 0, stream>>>(deg, blockBase, offs, cursor, N_NODES);
        k_scatter<<<dim3((N_EDGES + 255) / 256), blk, 0, stream>>>(row, col, cursor, adj, N_EDGES);
        k_gather_csr<<<dim3((N_NODES + 3) / 4), blk, 0, stream>>>(x, adj, offs, deg, out, N_NODES);
    }
}

// Round 5
// 149.542 us; speedup vs baseline: 1.0218x; 1.0218x over previous
//
#include <hip/hip_runtime.h>
#include <math.h>

// Problem constants (match reference)
#define N_NODES 50000
#define N_EDGES 800000
#define DFEAT   128
#define MAXNORM (1.0f - 4e-3f)   // (1 - BALL_EPS)/sqrt(c), c=1
#define CAP     32               // padded adjacency slots per row (deg ~ Poisson(16); P(deg>32)~1e-4 -> ovf)
#define OVF_CAP 8192
#define NPART   8                // row partitions (~XCDs)
#define PSIZE   (N_NODES / NPART) // 6250 rows per partition
#define SENT    N_NODES          // sentinel node id (xb row is zeros)

// clang-native vector type: __builtin_nontemporal_* accepts these (HIP_vector_type float4 is rejected)
typedef float vfloat4 __attribute__((ext_vector_type(4)));

// ==================== tier 1: fused build+convert, deg-scaled gather ====================

__device__ __forceinline__ void build_edge(int r, int c, int lo, int hi,
                                           int* __restrict__ deg,
                                           unsigned short* __restrict__ adj16,
                                           int* __restrict__ ovf, int* __restrict__ ovf_cnt) {
    if (r < lo || r >= hi || r == c) return;
    int pos = atomicAdd(&deg[r], 1);
    if (pos < CAP) adj16[r * CAP + pos] = (unsigned short)c;
    else {
        int o = atomicAdd(ovf_cnt, 1);
        if (o < OVF_CAP) { ovf[2 * o] = r; ovf[2 * o + 1] = c; }
    }
}

// FUSED build + x->bf16 conversion. The conversion (xb[node] = bf16(x[node]),
// UNSCALED — deg-independent!) has no ordering relation to the edge build, so
// both live in one kernel: each thread does its conversion task (if any) then
// its edge range. The x-read/xb-write HBM traffic overlaps the edge phase's
// atomic/L2 latency, and one launch+drain boundary disappears vs the old
// build -> prep chain. Row-partitioned edge build is unchanged (r11-proven):
// blocks with (blockIdx&7)==p handle only rows in partition p so deg atomics
// + adj stores stay in ONE XCD's L2; all partitions scan all edges via int4
// loads (4 edges per thread-iteration).
__global__ void k_build_conv(const int* __restrict__ row, const int* __restrict__ col,
                             const float* __restrict__ x,
                             int* __restrict__ deg, unsigned short* __restrict__ adj16,
                             unsigned int* __restrict__ xb,
                             int* __restrict__ ovf, int* __restrict__ ovf_cnt,
                             int e, int nprep) {
    // ---- phase A: unscaled bf16 conversion (grid-stride over nprep tasks) ----
    int gtid = blockIdx.x * blockDim.x + threadIdx.x;
    int nthr = gridDim.x * blockDim.x;
    for (int t = gtid; t < nprep; t += nthr) {
        int node = t >> 4;            // 16 tasks per row
        int part = t & 15;            // which 8-float chunk
        unsigned int w[4];
        if (node < N_NODES) {
            const vfloat4* x4 = (const vfloat4*)(x + (size_t)node * DFEAT + part * 8);
            vfloat4 a = __builtin_nontemporal_load(x4);      // x read once; don't pollute L2
            vfloat4 b = __builtin_nontemporal_load(x4 + 1);
            float fs[8] = {a.x, a.y, a.z, a.w, b.x, b.y, b.z, b.w};
            #pragma unroll
            for (int k = 0; k < 4; ++k) {
                unsigned int lo = __float_as_uint(fs[2 * k]);
                unsigned int hi = __float_as_uint(fs[2 * k + 1]);
                lo = (lo + 0x7FFFu + ((lo >> 16) & 1u)) >> 16;          // RNE to bf16
                hi = (hi + 0x7FFFu + ((hi >> 16) & 1u)) >> 16;
                w[k] = lo | (hi << 16);
            }
        } else {
            w[0] = w[1] = w[2] = w[3] = 0u;   // sentinel row: zeros
        }
        ((uint4*)xb)[t] = make_uint4(w[0], w[1], w[2], w[3]);
    }

    // ---- phase B: partitioned edge build ----
    int p      = blockIdx.x & (NPART - 1);
    int vblock = blockIdx.x >> 3;
    int tpp    = (gridDim.x >> 3) * blockDim.x;       // threads per partition
    int tid    = vblock * blockDim.x + threadIdx.x;   // 0..tpp-1 within partition
    int lo = p * PSIZE, hi = lo + PSIZE;

    int e4 = e >> 2;
    const int4* __restrict__ row4 = (const int4*)row;
    const int4* __restrict__ col4 = (const int4*)col;
    for (int i = tid; i < e4; i += tpp) {
        int4 r4 = row4[i];
        int4 c4 = col4[i];
        build_edge(r4.x, c4.x, lo, hi, deg, adj16, ovf, ovf_cnt);
        build_edge(r4.y, c4.y, lo, hi, deg, adj16, ovf, ovf_cnt);
        build_edge(r4.z, c4.z, lo, hi, deg, adj16, ovf, ovf_cnt);
        build_edge(r4.w, c4.w, lo, hi, deg, adj16, ovf, ovf_cnt);
    }
    for (int i = (e4 << 2) + tid; i < e; i += tpp)   // scalar tail (empty when e%4==0)
        build_edge(row[i], col[i], lo, hi, deg, adj16, ovf, ovf_cnt);
}

__device__ __forceinline__ float bf_lo(unsigned int w) { return __uint_as_float(w << 16); }
__device__ __forceinline__ float bf_hi(unsigned int w) { return __uint_as_float(w & 0xFFFF0000u); }

// One wave per destination row. xb is UNSCALED bf16(x); the per-neighbor
// normalization dis[c] = rsqrt(deg[c]+1) is applied here: deg[c[j]] is a
// wave-uniform-address load (broadcast, L2-hot from build) + one rsqrt per
// neighbor. Neighbors in chunks of 16 (8 independent uint2 loads per lane,
// batch-issued). Chunk 2 gated on wave-uniform capcnt>16 (P~0.43). deg>32
// rows (~1e-4) take the overflow list, scanned only by them.
// NOTE: masked lanes use c=SENT; xb[SENT] is the zero row, and deg[SENT]
// aliases ovf_cnt (layout: deg then ovf_cnt contiguous) — value irrelevant
// since the zero row nullifies the product; rsqrtf(>=1) is always finite.
__global__ __launch_bounds__(256) void k_gather_bf(const unsigned int* __restrict__ xb,
                                                   const unsigned short* __restrict__ adj16,
                                                   const int* __restrict__ deg,
                                                   const int* __restrict__ ovf,
                                                   const int* __restrict__ ovf_cnt,
                                                   float* __restrict__ out, int n) {
    int lane = threadIdx.x & 63;
    int half = lane >> 5;
    int fl   = lane & 31;
    int rowi = blockIdx.x * 4 + (threadIdx.x >> 6);
    if (rowi >= n) return;

    int cnt    = deg[rowi];
    int capcnt = cnt < CAP ? cnt : CAP;

    int a = SENT;
    if (lane < capcnt) a = (int)adj16[rowi * CAP + lane];  // coalesced 64B per row

    const unsigned int* __restrict__ xw = xb + 2 * fl;     // lane's word pair base

    // issue the self-row load early; it completes under the neighbor batches
    uint2 sv = *(const uint2*)(xw + rowi * (DFEAT / 2));

    float acc0 = 0.f, acc1 = 0.f, acc2 = 0.f, acc3 = 0.f;

    // chunk 1: neighbors 0..15
    {
        int c[8];
        #pragma unroll
        for (int j = 0; j < 8; ++j) c[j] = __shfl(a, 2 * j + half);
        uint2 v[8];
        int   d[8];
        #pragma unroll
        for (int j = 0; j < 8; ++j) { v[j] = *(const uint2*)(xw + c[j] * (DFEAT / 2)); d[j] = deg[c[j]]; }
        #pragma unroll
        for (int j = 0; j < 8; ++j) {
            float wgt = rsqrtf((float)(d[j] + 1));
            acc0 += wgt * bf_lo(v[j].x); acc1 += wgt * bf_hi(v[j].x);
            acc2 += wgt * bf_lo(v[j].y); acc3 += wgt * bf_hi(v[j].y);
        }
    }
    // chunk 2: neighbors 16..31 (wave-uniform branch, P ~ 0.43)
    if (capcnt > 16) {
        int c[8];
        #pragma unroll
        for (int j = 0; j < 8; ++j) c[j] = __shfl(a, 16 + 2 * j + half);
        uint2 v[8];
        int   d[8];
        #pragma unroll
        for (int j = 0; j < 8; ++j) { v[j] = *(const uint2*)(xw + c[j] * (DFEAT / 2)); d[j] = deg[c[j]]; }
        #pragma unroll
        for (int j = 0; j < 8; ++j) {
            float wgt = rsqrtf((float)(d[j] + 1));
            acc0 += wgt * bf_lo(v[j].x); acc1 += wgt * bf_hi(v[j].x);
            acc2 += wgt * bf_lo(v[j].y); acc3 += wgt * bf_hi(v[j].y);
        }
    }

    // overflow edges: only rows that actually overflowed scan the list
    if (cnt > CAP && half == 0) {
        int novf = *ovf_cnt;
        for (int k = 0; k < novf; ++k) {
            if (ovf[2 * k] == rowi) {
                int cc = ovf[2 * k + 1];
                uint2 v = *(const uint2*)(xw + cc * (DFEAT / 2));
                float wgt = rsqrtf((float)(deg[cc] + 1));
                acc0 += wgt * bf_lo(v.x); acc1 += wgt * bf_hi(v.x);
                acc2 += wgt * bf_lo(v.y); acc3 += wgt * bf_hi(v.y);
            }
        }
    }

    // combine halves (afterwards both halves hold identical full sums)
    acc0 += __shfl_xor(acc0, 32);
    acc1 += __shfl_xor(acc1, 32);
    acc2 += __shfl_xor(acc2, 32);
    acc3 += __shfl_xor(acc3, 32);

    float di = rsqrtf((float)(cnt + 1));             // dis[row]

    // self term: self-loop weight is di*di; add di*x_self before final *di
    acc0 += di * bf_lo(sv.x); acc1 += di * bf_hi(sv.x);
    acc2 += di * bf_lo(sv.y); acc3 += di * bf_hi(sv.y);

    acc0 *= di; acc1 *= di; acc2 *= di; acc3 *= di;

    // norm^2: reduce within each 32-half (halves identical)
    float nsq = acc0 * acc0 + acc1 * acc1 + acc2 * acc2 + acc3 * acc3;
    #pragma unroll
    for (int off = 16; off > 0; off >>= 1) nsq += __shfl_xor(nsq, off);

    float un = fmaxf(sqrtf(nsq), 1e-15f);
    float th = tanhf(un);
    float scale = th / un;                           // expmap0
    if (th > MAXNORM) scale *= MAXNORM / th;         // proj clamp (||p|| == tanh(un))

    if (half == 0) {
        vfloat4 o = { acc0 * scale, acc1 * scale, acc2 * scale, acc3 * scale };
        // written once, never re-read: non-temporal keeps xb resident in L2
        __builtin_nontemporal_store(o, (vfloat4*)(out + (size_t)rowi * DFEAT + 4 * fl));
    }
}

// ==================== fallback: CSR path (proven round-2) ====================

#define SCAN_BLK 256
#define NUM_SCAN_BLOCKS ((N_NODES + SCAN_BLK - 1) / SCAN_BLK)

__global__ void k_init_deg(int* __restrict__ deg, int n) {
    int i = blockIdx.x * blockDim.x + threadIdx.x;
    if (i < n) deg[i] = 1;
}

__global__ void k_hist(const int* __restrict__ row, const int* __restrict__ col,
                       int* __restrict__ deg, int e) {
    int i = blockIdx.x * blockDim.x + threadIdx.x;
    if (i < e) {
        int r = row[i], c = col[i];
        if (r != c) atomicAdd(&deg[r], 1);
    }
}

__global__ __launch_bounds__(SCAN_BLK) void k_block_sums(const int* __restrict__ deg,
                                                         int* __restrict__ blockSums, int n) {
    __shared__ int s[SCAN_BLK];
    int t = threadIdx.x;
    int i = blockIdx.x * SCAN_BLK + t;
    s[t] = (i < n) ? (deg[i] - 1) : 0;
    __syncthreads();
    for (int off = SCAN_BLK / 2; off > 0; off >>= 1) {
        if (t < off) s[t] += s[t + off];
        __syncthreads();
    }
    if (t == 0) blockSums[blockIdx.x] = s[0];
}

__global__ __launch_bounds__(SCAN_BLK) void k_scan_blocks(const int* __restrict__ blockSums,
                                                          int* __restrict__ blockBase) {
    __shared__ int s[SCAN_BLK];
    int t = threadIdx.x;
    s[t] = (t < NUM_SCAN_BLOCKS) ? blockSums[t] : 0;
    __syncthreads();
    for (int off = 1; off < SCAN_BLK; off <<= 1) {
        int v = (t >= off) ? s[t - off] : 0;
        __syncthreads();
        s[t] += v;
        __syncthreads();
    }
    if (t < NUM_SCAN_BLOCKS) blockBase[t] = (t == 0) ? 0 : s[t - 1];
}

__global__ __launch_bounds__(SCAN_BLK) void k_block_scan(const int* __restrict__ deg,
                                                         const int* __restrict__ blockBase,
                                                         int* __restrict__ offs,
                                                         int* __restrict__ cursor, int n) {
    __shared__ int s[SCAN_BLK];
    int t = threadIdx.x;
    int i = blockIdx.x * SCAN_BLK + t;
    int cnt = (i < n) ? (deg[i] - 1) : 0;
    s[t] = cnt;
    __syncthreads();
    for (int off = 1; off < SCAN_BLK; off <<= 1) {
        int v = (t >= off) ? s[t - off] : 0;
        __syncthreads();
        s[t] += v;
        __syncthreads();
    }
    if (i < n) {
        int excl = s[t] - cnt + blockBase[blockIdx.x];
        offs[i]   = excl;
        cursor[i] = excl;
    }
}

__global__ void k_scatter(const int* __restrict__ row, const int* __restrict__ col,
                          int* __restrict__ cursor, int* __restrict__ adj, int e) {
    int i = blockIdx.x * blockDim.x + threadIdx.x;
    if (i < e) {
        int r = row[i], c = col[i];
        if (r != c) {
            int pos = atomicAdd(&cursor[r], 1);
            adj[pos] = c;
        }
    }
}

__global__ __launch_bounds__(256) void k_gather_csr(const float* __restrict__ x,
                                                    const int* __restrict__ adj,
                                                    const int* __restrict__ offs,
                                                    const int* __restrict__ deg,
                                                    float* __restrict__ out, int n) {
    int lane = threadIdx.x & 63;
    int rowi = blockIdx.x * 4 + (threadIdx.x >> 6);
    if (rowi >= n) return;

    const float2* __restrict__ x2 = (const float2*)x;
    int beg = offs[rowi];
    int cnt = deg[rowi] - 1;

    float2 acc = make_float2(0.0f, 0.0f);
    for (int base = 0; base < cnt; base += 64) {
        int m = cnt - base; if (m > 64) m = 64;
        int a = 0;
        if (lane < m) a = adj[beg + base + lane];
        for (int nb = 0; nb < m; ++nb) {
            int c = __shfl(a, nb);
            float w = rsqrtf((float)deg[c]);
            float2 v = x2[c * (DFEAT / 2) + lane];
            acc.x += w * v.x;
            acc.y += w * v.y;
        }
    }
    float di = rsqrtf((float)deg[rowi]);
    float2 self = x2[rowi * (DFEAT / 2) + lane];
    acc.x = di * (acc.x + di * self.x);
    acc.y = di * (acc.y + di * self.y);

    float nsq = acc.x * acc.x + acc.y * acc.y;
    #pragma unroll
    for (int off = 32; off > 0; off >>= 1) nsq += __shfl_xor(nsq, off);

    float un = fmaxf(sqrtf(nsq), 1e-15f);
    float th = tanhf(un);
    float scale = th / un;
    if (th > MAXNORM) scale *= MAXNORM / th;

    float2 o = make_float2(acc.x * scale, acc.y * scale);
    ((float2*)out)[rowi * (DFEAT / 2) + lane] = o;
}

// ==================== launcher ====================

extern "C" void kernel_launch(void* const* d_in, const int* in_sizes, int n_in,
                              void* d_out, int out_size, void* d_ws, size_t ws_size,
                              hipStream_t stream) {
    const float* x          = (const float*)d_in[0];
    const int*   edge_index = (const int*)d_in[1];
    const int*   row = edge_index;            // [E]
    const int*   col = edge_index + N_EDGES;  // [E]
    float* out = (float*)d_out;
    char*  ws  = (char*)d_ws;

    size_t sz_xb    = sizeof(unsigned short) * (size_t)(N_NODES + 1) * DFEAT;  // 12.80 MB
    size_t sz_adj16 = sizeof(unsigned short) * (size_t)N_NODES * CAP;          //  3.20 MB
    size_t sz_deg   = sizeof(int) * (size_t)N_NODES;
    size_t need = sz_xb + sz_adj16 + sz_deg + sizeof(int) * (1 + 2 * (size_t)OVF_CAP);

    dim3 blk(256);
    if (ws_size >= need) {
        size_t off = 0;
        unsigned int*   xb      = (unsigned int*)(ws + off);   off += sz_xb;
        unsigned short* adj16   = (unsigned short*)(ws + off); off += sz_adj16;
        int*            deg     = (int*)(ws + off);            off += sz_deg;   // deg then ovf_cnt
        int*            ovf_cnt = (int*)(ws + off);            off += sizeof(int); // MUST stay contiguous
        int*            ovf     = (int*)(ws + off);                              // (deg[SENT] aliases ovf_cnt)

        int nprep = (N_NODES + 1) * (DFEAT / 8);   // 16 conversion tasks per row incl. sentinel
        // deg and ovf_cnt contiguous: one stream-ordered memset (graph-capturable)
        hipMemsetAsync(deg, 0, sz_deg + sizeof(int), stream);
        // fused build + unscaled bf16 conversion (3-dispatch pipeline)
        k_build_conv<<<dim3(8192), blk, 0, stream>>>(row, col, x, deg, adj16, xb, ovf, ovf_cnt, N_EDGES, nprep);
        k_gather_bf<<<dim3((N_NODES + 3) / 4), blk, 0, stream>>>(xb, adj16, deg, ovf, ovf_cnt, out, N_NODES);
    } else {
        size_t off = 0;
        int* deg       = (int*)(ws + off); off += sizeof(int) * (size_t)N_NODES;
        int* offs      = (int*)(ws + off); off += sizeof(int) * (size_t)N_NODES;
        int* cursor    = (int*)(ws + off); off += sizeof(int) * (size_t)N_NODES;
        int* blockSums = (int*)(ws + off); off += sizeof(int) * (size_t)NUM_SCAN_BLOCKS;
        int* blockBase = (int*)(ws + off); off += sizeof(int) * (size_t)NUM_SCAN_BLOCKS;
        int* adj       = (int*)(ws + off);

        k_init_deg<<<dim3((N_NODES + 255) / 256), blk, 0, stream>>>(deg, N_NODES);
        k_hist<<<dim3((N_EDGES + 255) / 256), blk, 0, stream>>>(row, col, deg, N_EDGES);
        k_block_sums<<<dim3(NUM_SCAN_BLOCKS), dim3(SCAN_BLK), 0, stream>>>(deg, blockSums, N_NODES);
        k_scan_blocks<<<dim3(1), dim3(SCAN_BLK), 0, stream>>>(blockSums, blockBase);
        k_block_scan<<<dim3(NUM_SCAN_BLOCKS), dim3(SCAN_BLK), 0, stream>>>(deg, blockBase, offs, cursor, N_NODES);
        k_scatter<<<dim3((N_EDGES + 255) / 256), blk, 0, stream>>>(row, col, cursor, adj, N_EDGES);
        k_gather_csr<<<dim3((N_NODES + 3) / 4), blk, 0, stream>>>(x, adj, offs, deg, out, N_NODES);
    }
}